// Round 10
// baseline (3355.432 us; speedup 1.0000x reference)
//
#include <hip/hip_runtime.h>
#include <hip/hip_bf16.h>
#include <hip/hip_cooperative_groups.h>

namespace cg = cooperative_groups;

#define BB 64
#define TT 64
#define FF 256
#define CC 64
#define GG 256   // 4*C
#define HP 264   // padded f-rows per batch: 4 zero + 256 + 4 zero
#define GST 264  // gates LDS row stride (floats)

using frag_ab = __attribute__((ext_vector_type(8))) short;  // 8 bf16
using f32x4   = __attribute__((ext_vector_type(4))) float;

__device__ __forceinline__ float sigmoidf_(float x) {
    return 1.0f / (1.0f + __expf(-x));
}
__device__ __forceinline__ float tanhf_(float x) {
    const float e = __expf(2.0f * x);
    return 1.0f - 2.0f / (e + 1.0f);
}
__device__ __forceinline__ void split2(float v, short* hi, short* lo) {
    __hip_bfloat16 h = __float2bfloat16(v);
    __hip_bfloat16 l = __float2bfloat16(v - __bfloat162float(h));
    *hi = *reinterpret_cast<short*>(&h);
    *lo = *reinterpret_cast<short*>(&l);
}

// ---- prep: Wh -> packed [p=(k*2+kk)][g][cin32] hi/lo; Wx -> [g][32] hi/lo;
//      h0 -> padded (B,HP,C) hi/lo with zeroed halo rows
__global__ __launch_bounds__(256) void prep_kernel(
    const float* __restrict__ Wh, const float* __restrict__ Wx,
    const float* __restrict__ h0,
    short* __restrict__ WhPh, short* __restrict__ WhPl,
    short* __restrict__ WxTh, short* __restrict__ WxTl,
    short* __restrict__ hGh, short* __restrict__ hGl)
{
    const int n = blockIdx.x * 256 + threadIdx.x;
    if (n < BB * HP * CC) {
        const int c = n & 63;
        const int r = (n >> 6) % HP;
        const int b = n / (HP * CC);
        if (r < 4 || r >= 260) {
            hGh[n] = 0; hGl[n] = 0;
        } else {
            split2(h0[(b * FF + (r - 4)) * CC + c], &hGh[n], &hGl[n]);
        }
    }
    if (n < 9 * GG * CC) {
        const int c32 = n & 31;
        const int g = (n >> 5) & 255;
        const int p = n >> 13;
        const int k = p >> 1;
        const int cin = (p & 1) * 32 + c32;
        split2(Wh[(k * CC + cin) * GG + g], &WhPh[n], &WhPl[n]);
    }
    if (n < GG * 32) {
        const int kz = n & 31;
        const int g = n >> 5;
        split2(kz < 9 ? Wx[kz * GG + g] : 0.0f, &WxTh[n], &WxTl[n]);
    }
}

// ---- cooperative: all 64 timesteps in one launch; 256 blocks (1/CU), 512 thr
__global__ __launch_bounds__(512, 2) void convlstm_all(
    const float* __restrict__ z,
    short* __restrict__ hGh, short* __restrict__ hGl,   // padded (B,HP,C) global h
    const float* __restrict__ c0,
    const short* __restrict__ WhPh, const short* __restrict__ WhPl,
    const short* __restrict__ WxTh, const short* __restrict__ WxTl,
    const float* __restrict__ bias,
    float* __restrict__ out)
{
    __shared__ __align__(16) char hbh[2][72 * 128];  // h hi tile, dbuf, swizzled
    __shared__ __align__(16) char hbl[2][72 * 128];  // h lo tile, dbuf
    __shared__ __align__(16) char zbh[64 * 64];      // z hi tile [64 f][32 kz]
    __shared__ __align__(16) char zbl[64 * 64];
    __shared__ __align__(16) float gbuf[32 * GST];   // gates fp32, two-pass

    cg::grid_group grid = cg::this_grid();

    const int b = blockIdx.x;
    const int f0 = blockIdx.y * 64;
    const int tid = threadIdx.x;
    const int lane = tid & 63;
    const int w = tid >> 6;          // 0..7 : owns g-cols [w*32, w*32+32)

    const int rA = lane & 15;
    const int sA = lane >> 4;
    const int gbase = w * 32;
    const int bln = rA * 32 + sA * 8;

    const float bv0 = bias[gbase + rA];
    const float bv1 = bias[gbase + 16 + rA];

    // ---- persistent c state in registers (this thread's 8 cells)
    const int flE = tid >> 4;             // epilogue row 0..31
    const int ch0E = (tid & 15) * 4;      // epilogue channel block
    const int cix0 = (b * FF + f0 + flE) * CC + ch0E;
    float4 cv0 = *reinterpret_cast<const float4*>(&c0[cix0]);
    float4 cv1 = *reinterpret_cast<const float4*>(&c0[cix0 + 32 * CC]);

    // ---- initial full h stage into buf0 (72 rows, padded space)
    for (int idx = tid; idx < 72 * 8; idx += 512) {
        const int row = idx >> 3, slot = idx & 7;
        const int off = (b * HP + f0 + row) * CC + slot * 8;
        const frag_ab vh = *reinterpret_cast<const frag_ab*>(hGh + off);
        const frag_ab vl = *reinterpret_cast<const frag_ab*>(hGl + off);
        const int a = row * 128 + ((slot ^ (row & 7)) << 4);
        *reinterpret_cast<frag_ab*>(&hbh[0][a]) = vh;
        *reinterpret_cast<frag_ab*>(&hbl[0][a]) = vl;
    }

    // ---- phase-0 B preload
    frag_ab cb[4];
    {
        const int o0 = gbase * 32 + bln;
        cb[0] = *reinterpret_cast<const frag_ab*>(WhPh + o0);
        cb[1] = *reinterpret_cast<const frag_ab*>(WhPh + o0 + 512);
        cb[2] = *reinterpret_cast<const frag_ab*>(WhPl + o0);
        cb[3] = *reinterpret_cast<const frag_ab*>(WhPl + o0 + 512);
    }

    #pragma unroll 1
    for (int t = 0; t < TT; ++t) {
        char* Hh = hbh[t & 1];        // current step's h tile
        char* Hl = hbl[t & 1];
        char* Nh = hbh[(t + 1) & 1];  // next step's h tile (epilogue writes)
        char* Nl = hbl[(t + 1) & 1];

        // ---- stage z tile [64 f][kz<9] hi+lo
        if (tid < 256) {
            const int row = tid >> 2, slot = tid & 3;
            const float* zr = z + ((long)b * TT + t) * FF;
            short vh[8], vl[8];
            #pragma unroll
            for (int j = 0; j < 8; ++j) {
                const int kz = slot * 8 + j;
                const int f = f0 + row - 4 + kz;
                const float val = (kz < 9 && f >= 0 && f < FF) ? zr[f] : 0.0f;
                split2(val, &vh[j], &vl[j]);
            }
            const int a = row * 64 + ((slot ^ (row & 3)) << 4);
            *reinterpret_cast<frag_ab*>(&zbh[a]) = *reinterpret_cast<frag_ab*>(vh);
            *reinterpret_cast<frag_ab*>(&zbl[a]) = *reinterpret_cast<frag_ab*>(vl);
        }
        // ---- stage 8 halo rows (0..3, 68..71) from global (t>0; interior is in LDS)
        if (t > 0 && tid < 128) {
            const int which = tid >> 6;     // 0: hi, 1: lo
            const int rr = tid & 63;
            int row = rr >> 3;
            row = (row < 4) ? row : row + 64;
            const int slot = rr & 7;
            const int off = (b * HP + f0 + row) * CC + slot * 8;
            const int a = row * 128 + ((slot ^ (row & 7)) << 4);
            if (which == 0)
                *reinterpret_cast<frag_ab*>(&Hh[a]) = *reinterpret_cast<const frag_ab*>(hGh + off);
            else
                *reinterpret_cast<frag_ab*>(&Hl[a]) = *reinterpret_cast<const frag_ab*>(hGl + off);
        }
        __syncthreads();

        f32x4 acc[4][2];
        #pragma unroll
        for (int Mt = 0; Mt < 4; ++Mt) {
            acc[Mt][0] = (f32x4){bv0, bv0, bv0, bv0};
            acc[Mt][1] = (f32x4){bv1, bv1, bv1, bv1};
        }

        // ---- 19 phases (18 Wh + z-tap); B prefetched one phase ahead
        #pragma unroll
        for (int p = 0; p < 19; ++p) {
            frag_ab nb[4];
            if (p < 17) {
                const int o0 = ((p + 1) * GG + gbase) * 32 + bln;
                nb[0] = *reinterpret_cast<const frag_ab*>(WhPh + o0);
                nb[1] = *reinterpret_cast<const frag_ab*>(WhPh + o0 + 512);
                nb[2] = *reinterpret_cast<const frag_ab*>(WhPl + o0);
                nb[3] = *reinterpret_cast<const frag_ab*>(WhPl + o0 + 512);
            } else if (p == 17) {
                const int o0 = gbase * 32 + bln;
                nb[0] = *reinterpret_cast<const frag_ab*>(WxTh + o0);
                nb[1] = *reinterpret_cast<const frag_ab*>(WxTh + o0 + 512);
                nb[2] = *reinterpret_cast<const frag_ab*>(WxTl + o0);
                nb[3] = *reinterpret_cast<const frag_ab*>(WxTl + o0 + 512);
            }
            frag_ab ah[4], al[4];
            if (p < 18) {
                const int k = p >> 1, kk = p & 1;
                const int sl = kk * 4 + sA;
                #pragma unroll
                for (int Mt = 0; Mt < 4; ++Mt) {
                    const int r = Mt * 16 + rA + k;
                    const int a = r * 128 + ((sl ^ (r & 7)) << 4);
                    ah[Mt] = *reinterpret_cast<const frag_ab*>(&Hh[a]);
                    al[Mt] = *reinterpret_cast<const frag_ab*>(&Hl[a]);
                }
            } else {
                #pragma unroll
                for (int Mt = 0; Mt < 4; ++Mt) {
                    const int r = Mt * 16 + rA;
                    const int a = r * 64 + ((sA ^ (r & 3)) << 4);
                    ah[Mt] = *reinterpret_cast<const frag_ab*>(&zbh[a]);
                    al[Mt] = *reinterpret_cast<const frag_ab*>(&zbl[a]);
                }
            }
            __builtin_amdgcn_s_setprio(1);
            #pragma unroll
            for (int Mt = 0; Mt < 4; ++Mt) {
                acc[Mt][0] = __builtin_amdgcn_mfma_f32_16x16x32_bf16(ah[Mt], cb[0], acc[Mt][0], 0, 0, 0);
                acc[Mt][1] = __builtin_amdgcn_mfma_f32_16x16x32_bf16(ah[Mt], cb[1], acc[Mt][1], 0, 0, 0);
            }
            #pragma unroll
            for (int Mt = 0; Mt < 4; ++Mt) {
                acc[Mt][0] = __builtin_amdgcn_mfma_f32_16x16x32_bf16(ah[Mt], cb[2], acc[Mt][0], 0, 0, 0);
                acc[Mt][1] = __builtin_amdgcn_mfma_f32_16x16x32_bf16(ah[Mt], cb[3], acc[Mt][1], 0, 0, 0);
            }
            #pragma unroll
            for (int Mt = 0; Mt < 4; ++Mt) {
                acc[Mt][0] = __builtin_amdgcn_mfma_f32_16x16x32_bf16(al[Mt], cb[0], acc[Mt][0], 0, 0, 0);
                acc[Mt][1] = __builtin_amdgcn_mfma_f32_16x16x32_bf16(al[Mt], cb[1], acc[Mt][1], 0, 0, 0);
            }
            __builtin_amdgcn_s_setprio(0);
            if (p < 18) { cb[0] = nb[0]; cb[1] = nb[1]; cb[2] = nb[2]; cb[3] = nb[3]; }
        }

        // ---- reload phase-0 B for NEXT step (latency hides under epilogue+sync)
        {
            const int o0 = gbase * 32 + bln;
            cb[0] = *reinterpret_cast<const frag_ab*>(WhPh + o0);
            cb[1] = *reinterpret_cast<const frag_ab*>(WhPh + o0 + 512);
            cb[2] = *reinterpret_cast<const frag_ab*>(WhPl + o0);
            cb[3] = *reinterpret_cast<const frag_ab*>(WhPl + o0 + 512);
        }

        // ---- two-pass epilogue through 32-row gbuf; h -> LDS(next)+global, c in regs
        #pragma unroll
        for (int pass = 0; pass < 2; ++pass) {
            if (pass) __syncthreads();   // pass-0 reads done before overwrite
            #pragma unroll
            for (int Mh = 0; Mh < 2; ++Mh) {
                const int Mt = pass * 2 + Mh;
                #pragma unroll
                for (int gtI = 0; gtI < 2; ++gtI) {
                    const int g = gbase + gtI * 16 + rA;
                    float* gp = &gbuf[(Mh * 16 + sA * 4) * GST + g];
                    gp[0]       = acc[Mt][gtI][0];
                    gp[GST]     = acc[Mt][gtI][1];
                    gp[2 * GST] = acc[Mt][gtI][2];
                    gp[3 * GST] = acc[Mt][gtI][3];
                }
            }
            __syncthreads();

            const int f = f0 + pass * 32 + flE;
            const float* gr = &gbuf[flE * GST];
            const f32x4 gi = *reinterpret_cast<const f32x4*>(gr + ch0E);
            const f32x4 gj = *reinterpret_cast<const f32x4*>(gr + 64 + ch0E);
            const f32x4 gf = *reinterpret_cast<const f32x4*>(gr + 128 + ch0E);
            const f32x4 go = *reinterpret_cast<const f32x4*>(gr + 192 + ch0E);

            float4& cvr = pass ? cv1 : cv0;
            const float co_[4] = {cvr.x, cvr.y, cvr.z, cvr.w};

            float hsum = 0.0f;
            float cv[4];
            short hh[4], hl[4];
            #pragma unroll
            for (int j = 0; j < 4; ++j) {
                const float cnew = co_[j] * sigmoidf_(gf[j] + 1.0f) + sigmoidf_(gi[j]) * tanhf_(gj[j]);
                const float hnew = tanhf_(cnew) * sigmoidf_(go[j]);
                cv[j] = cnew;
                split2(hnew, &hh[j], &hl[j]);
                hsum += hnew;
            }
            cvr = make_float4(cv[0], cv[1], cv[2], cv[3]);

            // global h (for neighbors' halos next step)
            const int hix = (b * HP + 4 + f) * CC + ch0E;
            *reinterpret_cast<uint2*>(&hGh[hix]) = *reinterpret_cast<uint2*>(hh);
            *reinterpret_cast<uint2*>(&hGl[hix]) = *reinterpret_cast<uint2*>(hl);
            // own LDS next-buffer interior (row = f-f0+4)
            const int r = pass * 32 + flE + 4;
            const int slot = ch0E >> 3;
            const int a = r * 128 + ((slot ^ (r & 7)) << 4) + (ch0E & 7) * 2;
            *reinterpret_cast<uint2*>(&Nh[a]) = *reinterpret_cast<uint2*>(hh);
            *reinterpret_cast<uint2*>(&Nl[a]) = *reinterpret_cast<uint2*>(hl);

            hsum += __shfl_xor(hsum, 1);
            hsum += __shfl_xor(hsum, 2);
            hsum += __shfl_xor(hsum, 4);
            hsum += __shfl_xor(hsum, 8);
            if ((tid & 15) == 0)
                out[(long)b * (TT * FF) + t * FF + f] = tanhf_(hsum * (1.0f / 64.0f));
        }

        if (t != TT - 1) grid.sync();
    }
}

extern "C" void kernel_launch(void* const* d_in, const int* in_sizes, int n_in,
                              void* d_out, int out_size, void* d_ws, size_t ws_size,
                              hipStream_t stream) {
    const float* z    = (const float*)d_in[0];
    const float* h0   = (const float*)d_in[1];
    const float* c0   = (const float*)d_in[2];
    const float* Wx   = (const float*)d_in[3];
    const float* Wh   = (const float*)d_in[4];
    const float* bias = (const float*)d_in[5];
    float* out = (float*)d_out;

    const int SEp = BB * HP * CC;   // 1,081,344 (padded h elems)
    short* hGh = (short*)d_ws;
    short* hGl = hGh + SEp;
    short* WhPh = hGl + SEp;
    short* WhPl = WhPh + 9 * GG * CC;
    short* WxTh = WhPl + 9 * GG * CC;
    short* WxTl = WxTh + GG * 32;

    prep_kernel<<<(SEp + 255) / 256, 256, 0, stream>>>(Wh, Wx, h0, WhPh, WhPl,
                                                       WxTh, WxTl, hGh, hGl);

    void* args[] = {
        (void*)&z, (void*)&hGh, (void*)&hGl, (void*)&c0,
        (void*)&WhPh, (void*)&WhPl, (void*)&WxTh, (void*)&WxTl,
        (void*)&bias, (void*)&out
    };
    hipLaunchCooperativeKernel((void*)convlstm_all,
                               dim3(BB, FF / 64), dim3(512),
                               args, 0, stream);
}

// Round 11
// 1083.052 us; speedup vs baseline: 3.0981x; 3.0981x over previous
//
#include <hip/hip_runtime.h>
#include <hip/hip_bf16.h>

#define BB 64
#define TT 64
#define FF 256
#define CC 64
#define GG 256   // 4*C
#define HP 264   // padded f-rows per batch: 4 zero + 256 + 4 zero
#define GST 264  // gates LDS row stride (floats)

using frag_ab = __attribute__((ext_vector_type(8))) short;   // 8 bf16
using f32x4   = __attribute__((ext_vector_type(4))) float;
using f32x16  = __attribute__((ext_vector_type(16))) float;

__device__ __forceinline__ float sigmoidf_(float x) {
    return 1.0f / (1.0f + __expf(-x));
}
__device__ __forceinline__ float tanhf_(float x) {
    const float e = __expf(2.0f * x);
    return 1.0f - 2.0f / (e + 1.0f);
}
__device__ __forceinline__ void split2(float v, short* hi, short* lo) {
    __hip_bfloat16 h = __float2bfloat16(v);
    __hip_bfloat16 l = __float2bfloat16(v - __bfloat162float(h));
    *hi = *reinterpret_cast<short*>(&h);
    *lo = *reinterpret_cast<short*>(&l);
}

// ---- prep: Wh -> [p36=k*4+s][g][e=16] hi/lo (cin = s*16+e); Wx -> [g][16] hi/lo;
//      h0 -> padded (B,HP,C) hi/lo with zeroed halo rows (both ping-pong buffers)
__global__ __launch_bounds__(256) void prep_kernel(
    const float* __restrict__ Wh, const float* __restrict__ Wx,
    const float* __restrict__ h0,
    short* __restrict__ WhBh, short* __restrict__ WhBl,
    short* __restrict__ WxBh, short* __restrict__ WxBl,
    short* __restrict__ hAh, short* __restrict__ hAl,
    short* __restrict__ hBh, short* __restrict__ hBl)
{
    const int n = blockIdx.x * 256 + threadIdx.x;
    if (n < BB * HP * CC) {
        const int c = n & 63;
        const int r = (n >> 6) % HP;
        const int b = n / (HP * CC);
        if (r < 4 || r >= 260) {
            hAh[n] = 0; hAl[n] = 0; hBh[n] = 0; hBl[n] = 0;
        } else {
            split2(h0[(b * FF + (r - 4)) * CC + c], &hAh[n], &hAl[n]);
        }
    }
    if (n < 36 * GG * 16) {     // 147,456
        const int e = n & 15;
        const int g = (n >> 4) & 255;
        const int p = n >> 12;          // 0..35
        const int k = p >> 2;
        const int cin = (p & 3) * 16 + e;
        split2(Wh[(k * CC + cin) * GG + g], &WhBh[n], &WhBl[n]);
    }
    if (n < GG * 16) {          // 4096
        const int e = n & 15;
        const int g = n >> 4;
        split2(e < 9 ? Wx[e * GG + g] : 0.0f, &WxBh[n], &WxBl[n]);
    }
}

// ---- one timestep: 32x32x16 MFMA; block=(b, 64-f-tile), 8 waves x 32 g-cols
__global__ __launch_bounds__(512, 2) void convlstm_step(
    const float* __restrict__ z,
    const short* __restrict__ hinh, const short* __restrict__ hinl,  // padded (B,HP,C)
    const float* __restrict__ c_in,
    const short* __restrict__ WhBh, const short* __restrict__ WhBl,
    const short* __restrict__ WxBh, const short* __restrict__ WxBl,
    const float* __restrict__ bias,
    short* __restrict__ houth, short* __restrict__ houtl,            // padded
    float* __restrict__ c_out,
    float* __restrict__ out, int t)
{
    __shared__ __align__(16) char hbyh[72 * 128];   // h hi tile, swizzled (9 KB)
    __shared__ __align__(16) char hbyl[72 * 128];   // h lo tile
    __shared__ __align__(16) char zbh[64 * 48];     // z hi tile [64 f][16 kz + pad]
    __shared__ __align__(16) char zbl[64 * 48];
    __shared__ __align__(16) float gbuf[32 * GST];  // gates fp32, two-pass (33.8 KB)

    const int b = blockIdx.x;
    const int f0 = blockIdx.y * 64;
    const int tid = threadIdx.x;
    const int lane = tid & 63;
    const int w = tid >> 6;          // 0..7 : owns g-cols [w*32, w*32+32)

    const int l31 = lane & 31;
    const int hf = lane >> 5;        // 0..1 : k-half
    const int gbase = w * 32;
    const int gq = gbase + l31;      // this lane's B column

    // ---- early global loads: B ring (phases 0,1) + epilogue c + bias
    frag_ab b0h, b0l, b1h, b1l;
    {
        const int o0 = gq * 16 + hf * 8;              // p=0
        const int o1 = (256 + gq) * 16 + hf * 8;      // p=1
        b0h = *reinterpret_cast<const frag_ab*>(WhBh + o0);
        b0l = *reinterpret_cast<const frag_ab*>(WhBl + o0);
        b1h = *reinterpret_cast<const frag_ab*>(WhBh + o1);
        b1l = *reinterpret_cast<const frag_ab*>(WhBl + o1);
    }
    const float bv = bias[gq];
    const int flE = tid >> 4;             // epilogue row 0..31
    const int ch0E = (tid & 15) * 4;      // epilogue channel block
    const int cixE0 = (b * FF + f0 + flE) * CC + ch0E;
    const float4 cold0 = *reinterpret_cast<const float4*>(&c_in[cixE0]);
    const float4 cold1 = *reinterpret_cast<const float4*>(&c_in[cixE0 + 32 * CC]);

    // ---- stage h tile rows f0..f0+71 (padded space; always in-bounds)
    for (int idx = tid; idx < 72 * 8; idx += 512) {
        const int row = idx >> 3, slot = idx & 7;
        const int off = (b * HP + f0 + row) * CC + slot * 8;
        const frag_ab vh = *reinterpret_cast<const frag_ab*>(hinh + off);
        const frag_ab vl = *reinterpret_cast<const frag_ab*>(hinl + off);
        const int a = row * 128 + ((slot ^ (row & 7)) << 4);
        *reinterpret_cast<frag_ab*>(&hbyh[a]) = vh;
        *reinterpret_cast<frag_ab*>(&hbyl[a]) = vl;
    }
    // ---- stage z tile [64 f][kz 0..15] hi+lo (48B rows: 32B data + 16B pad)
    if (tid < 128) {
        const int row = tid >> 1, half = tid & 1;
        const float* zr = z + ((long)b * TT + t) * FF;
        short vh[8], vl[8];
        #pragma unroll
        for (int j = 0; j < 8; ++j) {
            const int kz = half * 8 + j;
            const int f = f0 + row - 4 + kz;
            const float val = (kz < 9 && f >= 0 && f < FF) ? zr[f] : 0.0f;
            split2(val, &vh[j], &vl[j]);
        }
        const int a = row * 48 + half * 16;
        *reinterpret_cast<frag_ab*>(&zbh[a]) = *reinterpret_cast<frag_ab*>(vh);
        *reinterpret_cast<frag_ab*>(&zbl[a]) = *reinterpret_cast<frag_ab*>(vl);
    }
    __syncthreads();

    f32x16 acc[2];
    #pragma unroll
    for (int r = 0; r < 16; ++r) { acc[0][r] = bv; acc[1][r] = bv; }

    // ---- 37 phases: 36 Wh K=16 slices (k=p>>2, s=p&3) + 1 z slice; B 2-deep ring
    #pragma unroll
    for (int p = 0; p < 37; ++p) {
        frag_ab nbh, nbl;
        if (p + 2 < 36) {
            const int o = ((p + 2) * 256 + gq) * 16 + hf * 8;
            nbh = *reinterpret_cast<const frag_ab*>(WhBh + o);
            nbl = *reinterpret_cast<const frag_ab*>(WhBl + o);
        } else if (p + 2 == 36) {
            const int o = gq * 16 + hf * 8;
            nbh = *reinterpret_cast<const frag_ab*>(WxBh + o);
            nbl = *reinterpret_cast<const frag_ab*>(WxBl + o);
        }
        frag_ab ah[2], al[2];
        if (p < 36) {
            const int k = p >> 2, s = p & 3;
            const int sl = s * 2 + hf;
            #pragma unroll
            for (int Mt = 0; Mt < 2; ++Mt) {
                const int r = Mt * 32 + l31 + k;
                const int a = r * 128 + ((sl ^ (r & 7)) << 4);
                ah[Mt] = *reinterpret_cast<const frag_ab*>(&hbyh[a]);
                al[Mt] = *reinterpret_cast<const frag_ab*>(&hbyl[a]);
            }
        } else {
            #pragma unroll
            for (int Mt = 0; Mt < 2; ++Mt) {
                const int a = (Mt * 32 + l31) * 48 + hf * 16;
                ah[Mt] = *reinterpret_cast<const frag_ab*>(&zbh[a]);
                al[Mt] = *reinterpret_cast<const frag_ab*>(&zbl[a]);
            }
        }
        __builtin_amdgcn_s_setprio(1);
        #pragma unroll
        for (int Mt = 0; Mt < 2; ++Mt)
            acc[Mt] = __builtin_amdgcn_mfma_f32_32x32x16_bf16(ah[Mt], b0h, acc[Mt], 0, 0, 0);
        #pragma unroll
        for (int Mt = 0; Mt < 2; ++Mt)
            acc[Mt] = __builtin_amdgcn_mfma_f32_32x32x16_bf16(ah[Mt], b0l, acc[Mt], 0, 0, 0);
        #pragma unroll
        for (int Mt = 0; Mt < 2; ++Mt)
            acc[Mt] = __builtin_amdgcn_mfma_f32_32x32x16_bf16(al[Mt], b0h, acc[Mt], 0, 0, 0);
        __builtin_amdgcn_s_setprio(0);
        b0h = b1h; b0l = b1l; b1h = nbh; b1l = nbl;
    }

    // ---- two-pass epilogue through 32-row gbuf (pass = M-tile)
    #pragma unroll
    for (int pass = 0; pass < 2; ++pass) {
        if (pass) __syncthreads();   // pass-0 reads done before overwrite
        // scatter: C layout col=lane&31, row=(reg&3)+8*(reg>>2)+4*hf
        #pragma unroll
        for (int reg = 0; reg < 16; ++reg) {
            const int crow = (reg & 3) + 8 * (reg >> 2) + 4 * hf;
            gbuf[crow * GST + gq] = acc[pass][reg];
        }
        __syncthreads();

        const int f = f0 + pass * 32 + flE;
        const float* gr = &gbuf[flE * GST];
        const f32x4 gi = *reinterpret_cast<const f32x4*>(gr + ch0E);
        const f32x4 gj = *reinterpret_cast<const f32x4*>(gr + 64 + ch0E);
        const f32x4 gf = *reinterpret_cast<const f32x4*>(gr + 128 + ch0E);
        const f32x4 go = *reinterpret_cast<const f32x4*>(gr + 192 + ch0E);

        const float4 cold = pass ? cold1 : cold0;
        const float co_[4] = {cold.x, cold.y, cold.z, cold.w};

        float hsum = 0.0f;
        float cv[4];
        short hh[4], hl[4];
        #pragma unroll
        for (int j = 0; j < 4; ++j) {
            const float cnew = co_[j] * sigmoidf_(gf[j] + 1.0f) + sigmoidf_(gi[j]) * tanhf_(gj[j]);
            const float hnew = tanhf_(cnew) * sigmoidf_(go[j]);
            cv[j] = cnew;
            split2(hnew, &hh[j], &hl[j]);
            hsum += hnew;
        }
        const int cix = (b * FF + f) * CC + ch0E;
        *reinterpret_cast<float4*>(&c_out[cix]) = make_float4(cv[0], cv[1], cv[2], cv[3]);
        const int hix = (b * HP + 4 + f) * CC + ch0E;
        *reinterpret_cast<uint2*>(&houth[hix]) = *reinterpret_cast<uint2*>(hh);
        *reinterpret_cast<uint2*>(&houtl[hix]) = *reinterpret_cast<uint2*>(hl);

        hsum += __shfl_xor(hsum, 1);
        hsum += __shfl_xor(hsum, 2);
        hsum += __shfl_xor(hsum, 4);
        hsum += __shfl_xor(hsum, 8);
        if ((tid & 15) == 0)
            out[(long)b * (TT * FF) + t * FF + f] = tanhf_(hsum * (1.0f / 64.0f));
    }
}

extern "C" void kernel_launch(void* const* d_in, const int* in_sizes, int n_in,
                              void* d_out, int out_size, void* d_ws, size_t ws_size,
                              hipStream_t stream) {
    const float* z    = (const float*)d_in[0];
    const float* h0   = (const float*)d_in[1];
    const float* c0   = (const float*)d_in[2];
    const float* Wx   = (const float*)d_in[3];
    const float* Wh   = (const float*)d_in[4];
    const float* bias = (const float*)d_in[5];
    float* out = (float*)d_out;

    const int SEp = BB * HP * CC;   // 1,081,344 (padded h elems)
    const int SE  = BB * FF * CC;   // 1,048,576
    short* hAh = (short*)d_ws;
    short* hAl = hAh + SEp;
    short* hBh = hAl + SEp;
    short* hBl = hBh + SEp;
    float* cW  = (float*)(hBl + SEp);
    short* WhBh = (short*)(cW + SE);
    short* WhBl = WhBh + 36 * GG * 16;
    short* WxBh = WhBl + 36 * GG * 16;
    short* WxBl = WxBh + GG * 16;

    prep_kernel<<<(SEp + 255) / 256, 256, 0, stream>>>(Wh, Wx, h0, WhBh, WhBl,
                                                       WxBh, WxBl, hAh, hAl, hBh, hBl);

    dim3 grid(BB, FF / 64);  // 64 x 4 = 256 blocks (1/CU)
    for (int t = 0; t < TT; ++t) {
        const short* hih = (t & 1) ? hBh : hAh;
        const short* hil = (t & 1) ? hBl : hAl;
        short* hoh = (t & 1) ? hAh : hBh;
        short* hol = (t & 1) ? hAl : hBl;
        const float* cin = (t == 0) ? c0 : cW;
        convlstm_step<<<grid, 512, 0, stream>>>(z, hih, hil, cin,
                                                WhBh, WhBl, WxBh, WxBl, bias,
                                                hoh, hol, cW, out, t);
    }
}